// Round 1
// baseline (118.117 us; speedup 1.0000x reference)
//
#include <hip/hip_runtime.h>
#include <hip/hip_bf16.h>

#define IN_DIM 2
#define OUT_DIM 3
#define HID 16

// One point per thread. All weights are wave-uniform -> scalar loads (K$),
// so the VALU does only the 912 FMAs/point. ReLU = v_max_f32.
__global__ __launch_bounds__(256) void mlp3_kernel(
    const float* __restrict__ x,
    const float* __restrict__ W1,  // [3][2][16]
    const float* __restrict__ b1,  // [3][16]
    const float* __restrict__ W2,  // [3][16][16]
    const float* __restrict__ b2,  // [3][16]
    const float* __restrict__ W3,  // [3][16]
    const float* __restrict__ b3,  // [3]
    float* __restrict__ out,       // [N][3]
    int n)
{
    int i = blockIdx.x * blockDim.x + threadIdx.x;
    if (i >= n) return;

    const float2 xv = *reinterpret_cast<const float2*>(x + 2 * (size_t)i);

    float y[OUT_DIM];

    #pragma unroll
    for (int e = 0; e < OUT_DIM; ++e) {
        const float* w1  = W1 + e * IN_DIM * HID;   // [2][16] row-major (i, h)
        const float* bb1 = b1 + e * HID;
        const float* w2  = W2 + e * HID * HID;      // [16][16] row-major (k, j)
        const float* bb2 = b2 + e * HID;
        const float* w3  = W3 + e * HID;

        // Layer 1: h1[h] = relu(x0*W1[0][h] + x1*W1[1][h] + b1[h])
        float h1[HID];
        #pragma unroll
        for (int h = 0; h < HID; ++h) {
            float v = fmaf(xv.x, w1[h], fmaf(xv.y, w1[HID + h], bb1[h]));
            h1[h] = fmaxf(v, 0.0f);
        }

        // Layer 2: h2[j] = relu(sum_k h1[k] * W2[k][j] + b2[j])
        float h2[HID];
        #pragma unroll
        for (int j = 0; j < HID; ++j) h2[j] = bb2[j];
        #pragma unroll
        for (int k = 0; k < HID; ++k) {
            float a = h1[k];
            #pragma unroll
            for (int j = 0; j < HID; ++j) {
                h2[j] = fmaf(a, w2[k * HID + j], h2[j]);
            }
        }

        // Layer 3: y = sum_j relu(h2[j]) * W3[j] + b3
        float acc = b3[e];
        #pragma unroll
        for (int j = 0; j < HID; ++j) {
            acc = fmaf(fmaxf(h2[j], 0.0f), w3[j], acc);
        }
        y[e] = acc;
    }

    float* o = out + 3 * (size_t)i;
    o[0] = y[0];
    o[1] = y[1];
    o[2] = y[2];
}

extern "C" void kernel_launch(void* const* d_in, const int* in_sizes, int n_in,
                              void* d_out, int out_size, void* d_ws, size_t ws_size,
                              hipStream_t stream) {
    const float* x  = (const float*)d_in[0];
    const float* W1 = (const float*)d_in[1];
    const float* b1 = (const float*)d_in[2];
    const float* W2 = (const float*)d_in[3];
    const float* b2 = (const float*)d_in[4];
    const float* W3 = (const float*)d_in[5];
    const float* b3 = (const float*)d_in[6];
    float* out = (float*)d_out;

    const int n = in_sizes[0] / IN_DIM;  // 4194304
    const int block = 256;
    const int grid = (n + block - 1) / block;

    mlp3_kernel<<<grid, block, 0, stream>>>(x, W1, b1, W2, b2, W3, b3, out, n);
}

// Round 2
// 78.529 us; speedup vs baseline: 1.5041x; 1.5041x over previous
//
#include <hip/hip_runtime.h>
#include <hip/hip_bf16.h>

#define NH 3

typedef __attribute__((ext_vector_type(4))) float f32x4;
typedef __attribute__((ext_vector_type(4))) short s16x4;
typedef __attribute__((ext_vector_type(4))) __bf16 bf16x4;

// f32x4 -> 4 bf16 (RNE) bit-packed as short4, ready as MFMA A/B operand.
static __device__ __forceinline__ s16x4 cvt4(f32x4 v) {
    return __builtin_bit_cast(s16x4, __builtin_convertvector(v, bf16x4));
}

#define MFMA16(A, B, C) __builtin_amdgcn_mfma_f32_16x16x16bf16_1k((A), (B), (C), 0, 0, 0)

// Layout identity used throughout (16x16 MFMA family):
//   B operand: lane holds B[k=4*(lane>>4)+elem][col=lane&15]
//   C/D:       lane holds D[row=4*(lane>>4)+reg][col=lane&15]
// => D of one MFMA is bit-compatible with B of the next (k := row).
// Chain (all transposed, col = point):
//   D1[k_hid][p] = W1^T x^T + b1      (A=W1 frag, B=x frag, C=b1)
//   D2[j][p]     = W2^T relu(D1) + b2 (A=W2 frag, B=relu(D1), C=b2)
//   y[p]         = 1^T (relu(D2)*W3) + b3  (A=ones, B=t frag, C=b3; all rows equal)
__global__ __launch_bounds__(256) void mlp3_mfma(
    const float* __restrict__ x,
    const float* __restrict__ W1, const float* __restrict__ b1,
    const float* __restrict__ W2, const float* __restrict__ b2,
    const float* __restrict__ W3, const float* __restrict__ b3,
    float* __restrict__ out, int n)
{
    const int lane = (int)(threadIdx.x & 63);
    const int col  = lane & 15;   // matrix column = point-in-tile; also row for A frags
    const int g    = lane >> 4;   // k-slice group
    const int kb   = g << 2;      // k base = 4g

    s16x4 a1[NH], a2[NH];
    f32x4 c1[NH], c2[NH], c3[NH], w3v[NH];

    #pragma unroll
    for (int e = 0; e < NH; ++e) {
        // A1[row=k_hid][k_in]: W1[e][k_in][k_hid]; only k_in<2 nonzero (g==0, elems 0,1)
        float w1a = 0.f, w1b = 0.f;
        if (g == 0) {
            w1a = W1[e * 32 + col];        // W1[e][0][col]
            w1b = W1[e * 32 + 16 + col];   // W1[e][1][col]
        }
        f32x4 t1 = {w1a, w1b, 0.f, 0.f};
        a1[e] = cvt4(t1);
        // A2[row=j][k_hid] = W2[e][k_hid][j], j = col, k_hid = kb+i
        f32x4 t2;
        #pragma unroll
        for (int i = 0; i < 4; ++i) t2[i] = W2[e * 256 + (kb + i) * 16 + col];
        a2[e] = cvt4(t2);
        #pragma unroll
        for (int r = 0; r < 4; ++r) {
            c1[e][r]  = b1[e * 16 + kb + r];
            c2[e][r]  = b2[e * 16 + kb + r];
            w3v[e][r] = W3[e * 16 + kb + r];
            c3[e][r]  = b3[e];
        }
    }

    const s16x4 aone = { (short)0x3F80, (short)0x3F80, (short)0x3F80, (short)0x3F80 };

    const int wave   = (int)((blockIdx.x * blockDim.x + threadIdx.x) >> 6);
    const int nwav   = (int)((gridDim.x * blockDim.x) >> 6);
    const int nchunk = (n + 63) >> 6;

    for (int c = wave; c < nchunk; c += nwav) {
        const int base = c << 6;
        #pragma unroll
        for (int t = 0; t < 4; ++t) {
            const int p  = base + t * 16 + col;
            const int pc = p < n ? p : n - 1;
            const float2 xv = *reinterpret_cast<const float2*>(x + 2 * (size_t)pc);
            // B1[k_in][p]: only g==0 lanes carry (x0,x1) in elems 0,1
            f32x4 xs = {0.f, 0.f, 0.f, 0.f};
            if (g == 0) { xs[0] = xv.x; xs[1] = xv.y; }
            const s16x4 bx = cvt4(xs);

            float ys0 = 0.f, ys1 = 0.f, ys2 = 0.f;
            #pragma unroll
            for (int e = 0; e < NH; ++e) {
                f32x4 h1 = MFMA16(a1[e], bx, c1[e]);           // h1^T[k][p] + b1
                f32x4 r1;
                #pragma unroll
                for (int r = 0; r < 4; ++r) r1[r] = fmaxf(h1[r], 0.f);
                s16x4 bh = cvt4(r1);
                f32x4 h2 = MFMA16(a2[e], bh, c2[e]);           // h2^T[j][p] + b2
                f32x4 r2;
                #pragma unroll
                for (int r = 0; r < 4; ++r) r2[r] = fmaxf(h2[r], 0.f) * w3v[e][r];
                s16x4 bt = cvt4(r2);
                f32x4 yv = MFMA16(aone, bt, c3[e]);            // y[p] + b3 (all rows)
                if (e == 0) ys0 = yv[0];
                else if (e == 1) ys1 = yv[0];
                else ys2 = yv[0];
            }
            // Store: group g writes head g's value for its column-point.
            if (g < NH && p < n) {
                float ysel = (g == 0) ? ys0 : ((g == 1) ? ys1 : ys2);
                out[(size_t)p * NH + g] = ysel;
            }
        }
    }
}

extern "C" void kernel_launch(void* const* d_in, const int* in_sizes, int n_in,
                              void* d_out, int out_size, void* d_ws, size_t ws_size,
                              hipStream_t stream) {
    const float* x  = (const float*)d_in[0];
    const float* W1 = (const float*)d_in[1];
    const float* b1 = (const float*)d_in[2];
    const float* W2 = (const float*)d_in[3];
    const float* b2 = (const float*)d_in[4];
    const float* W3 = (const float*)d_in[5];
    const float* b3 = (const float*)d_in[6];
    float* out = (float*)d_out;
    (void)d_ws; (void)ws_size; (void)n_in; (void)out_size;

    const int n = in_sizes[0] / 2;  // 4194304 points
    const int block = 256;
    const int grid = 2048;          // 8192 waves, 8 chunks of 64 points each

    mlp3_mfma<<<grid, block, 0, stream>>>(x, W1, b1, W2, b2, W3, b3, out, n);
}

// Round 4
// 65.238 us; speedup vs baseline: 1.8106x; 1.2037x over previous
//
#include <hip/hip_runtime.h>
#include <hip/hip_bf16.h>

#define NH 3

typedef __attribute__((ext_vector_type(4))) float f32x4;
typedef __attribute__((ext_vector_type(4))) short s16x4;
typedef __attribute__((ext_vector_type(4))) __bf16 bf16x4;

// f32x4 -> 4 bf16 (RNE), compiler-lowered (known-good from R2; m240: compiler
// handles bf16 cvt well on gfx950).
static __device__ __forceinline__ s16x4 cvt4(f32x4 v) {
    return __builtin_bit_cast(s16x4, __builtin_convertvector(v, bf16x4));
}

#define MFMA16(A, B, C) __builtin_amdgcn_mfma_f32_16x16x16bf16_1k((A), (B), (C), 0, 0, 0)

// Chain (all transposed, col = point), using D-layout == B-layout identity:
//   D1[k][p] = W1^T x^T + b1            (A1 = W1 frag, B = x frag, C = b1)
//   D2[j][p] = W2^T relu(D1) + b2       (A2 = W2 frag, B = relu(D1), C = b2)
//   y[p]     = sum_k w3[k] relu(D2)[k][p] + b3   (A3[r][k] = w3[k] bcast rows, C = b3)
__global__ __launch_bounds__(256, 4) void mlp3_mfma(
    const float* __restrict__ x,
    const float* __restrict__ W1, const float* __restrict__ b1,
    const float* __restrict__ W2, const float* __restrict__ b2,
    const float* __restrict__ W3, const float* __restrict__ b3,
    float* __restrict__ out, int n)
{
    const int tid  = (int)threadIdx.x;
    const int lane = tid & 63;
    const int col  = lane & 15;   // matrix column = point-in-tile; row index for A frags
    const int g    = lane >> 4;   // k-slice group
    const int kb   = g << 2;
    const int wv   = tid >> 6;    // wave id within block (0..3)

    // ---- weight fragments (loaded once, resident in VGPRs) ----
    s16x4 a1[NH], a2[NH], a3[NH];
    f32x4 c1[NH], c2[NH], c3[NH];
    #pragma unroll
    for (int e = 0; e < NH; ++e) {
        float w1a = 0.f, w1b = 0.f;
        if (g == 0) {                       // A1 rows=hid(col), k=in; only k<2 nonzero
            w1a = W1[e * 32 + col];
            w1b = W1[e * 32 + 16 + col];
        }
        f32x4 t1 = {w1a, w1b, 0.f, 0.f};
        a1[e] = cvt4(t1);
        // A2[row=j=col][k=kb+i] = W2[e][kb+i][col]
        f32x4 t2;
        #pragma unroll
        for (int i = 0; i < 4; ++i) t2[i] = W2[e * 256 + (kb + i) * 16 + col];
        a2[e] = cvt4(t2);
        // A3[row=col][k=kb+i] = W3[e][kb+i]  (broadcast over rows)
        f32x4 t3;
        #pragma unroll
        for (int i = 0; i < 4; ++i) t3[i] = W3[e * 16 + kb + i];
        a3[e] = cvt4(t3);
        #pragma unroll
        for (int r = 0; r < 4; ++r) {
            c1[e][r] = b1[e * 16 + kb + r];
            c2[e][r] = b2[e * 16 + kb + r];
            c3[e][r] = b3[e];
        }
    }

    // ---- per-lane byte offsets (32-bit); uniform bases advance per iteration ----
    const int xoff = (wv * 64 + col) * 8;            // + t*128 imm
    const int ooff = (wv * 192 + col * 3 + g) * 4;   // + t*192 imm (g<3 only)
    const bool gz = (g == 0);
    const bool g1 = (g == 1);

    const int nblk = n >> 8;                         // 256 points per block-iter
    for (int cb = blockIdx.x; cb < nblk; cb += gridDim.x) {
        const char* xb = (const char*)x + (size_t)cb * 2048;
        char*       ob = (char*)out + (size_t)cb * 3072;

        float ys[4];
        #pragma unroll
        for (int t = 0; t < 4; ++t) {
            const float2 xv = *reinterpret_cast<const float2*>(xb + xoff + t * 128);
            f32x4 xs = {0.f, 0.f, 0.f, 0.f};
            if (gz) { xs[0] = xv.x; xs[1] = xv.y; }  // B1: only g==0 lanes carry x
            const s16x4 bx = cvt4(xs);

            float y0, y1, y2;
            #pragma unroll
            for (int e = 0; e < NH; ++e) {
                f32x4 h1 = MFMA16(a1[e], bx, c1[e]);
                f32x4 r1;
                #pragma unroll
                for (int r = 0; r < 4; ++r) r1[r] = fmaxf(h1[r], 0.f);
                s16x4 bh = cvt4(r1);
                f32x4 h2 = MFMA16(a2[e], bh, c2[e]);
                f32x4 r2;
                #pragma unroll
                for (int r = 0; r < 4; ++r) r2[r] = fmaxf(h2[r], 0.f);
                s16x4 bt = cvt4(r2);
                f32x4 yv = MFMA16(a3[e], bt, c3[e]);  // rows identical: y + b3
                if      (e == 0) y0 = yv[0];
                else if (e == 1) y1 = yv[0];
                else             y2 = yv[0];
            }
            ys[t] = gz ? y0 : (g1 ? y1 : y2);
        }

        if (g < NH) {
            #pragma unroll
            for (int t = 0; t < 4; ++t)
                *reinterpret_cast<float*>(ob + ooff + t * 192) = ys[t];
        }
    }
}

extern "C" void kernel_launch(void* const* d_in, const int* in_sizes, int n_in,
                              void* d_out, int out_size, void* d_ws, size_t ws_size,
                              hipStream_t stream) {
    const float* x  = (const float*)d_in[0];
    const float* W1 = (const float*)d_in[1];
    const float* b1 = (const float*)d_in[2];
    const float* W2 = (const float*)d_in[3];
    const float* b2 = (const float*)d_in[4];
    const float* W3 = (const float*)d_in[5];
    const float* b3 = (const float*)d_in[6];
    float* out = (float*)d_out;
    (void)d_ws; (void)ws_size; (void)n_in; (void)out_size;

    const int n = in_sizes[0] / 2;   // 4194304 points (16384 * 256)
    const int block = 256;
    const int grid = 2048;

    mlp3_mfma<<<grid, block, 0, stream>>>(x, W1, b1, W2, b2, W3, b3, out, n);
}

// Round 5
// 59.787 us; speedup vs baseline: 1.9756x; 1.0912x over previous
//
#include <hip/hip_runtime.h>
#include <hip/hip_bf16.h>

typedef __attribute__((ext_vector_type(4))) float f32x4;
typedef __attribute__((ext_vector_type(4))) short s16x4;
typedef __attribute__((ext_vector_type(4))) __bf16 bf16x4;

// f32x4 -> 4 bf16 (RNE), compiler-lowered.
static __device__ __forceinline__ s16x4 cvt4(f32x4 v) {
    return __builtin_bit_cast(s16x4, __builtin_convertvector(v, bf16x4));
}

#define MFMA16(A, B, C) __builtin_amdgcn_mfma_f32_16x16x16bf16_1k((A), (B), (C), 0, 0, 0)

// All transposed, col = point. D-layout == B-layout identity chains the MFMAs.
//   MFMA1: D1[k][p] = W1^T x^T (+ b1 via K-slot 2, x-slot 2 = 1.0), C = 0
//   MFMA2: D2[j][p] = W2^T relu(D1) + b2 (C = b2)
//   MFMA3: y[p]     = sum_k w3[k] relu(D2)[k][p]  (A3 rows = w3 bcast, C = 0)
//   y += b3 scalar post-add; lane-group g stores head g.
__global__ __launch_bounds__(256, 8) void mlp3_mfma(
    const float* __restrict__ x,
    const float* __restrict__ W1, const float* __restrict__ b1,
    const float* __restrict__ W2, const float* __restrict__ b2,
    const float* __restrict__ W3, const float* __restrict__ b3,
    float* __restrict__ out, int n)
{
    const int tid  = (int)threadIdx.x;
    const int lane = tid & 63;
    const int col  = lane & 15;   // matrix column = point; row index for A frags
    const int g    = lane >> 4;   // k-slice group
    const int kb   = g << 2;
    const int wv   = tid >> 6;

    // ---- weight fragments (loaded once; total live set targeted <= 64 regs) ----
    s16x4 a1[3], a2[3], a3[3];
    f32x4 c2[3];
    #pragma unroll
    for (int e = 0; e < 3; ++e) {
        float w1a = 0.f, w1b = 0.f, w1c = 0.f;
        if (g == 0) {                         // A1 row=col(hid), k: 0=x0 w, 1=x1 w, 2=b1
            w1a = W1[e * 32 + col];
            w1b = W1[e * 32 + 16 + col];
            w1c = b1[e * 16 + col];
        }
        f32x4 t1 = {w1a, w1b, w1c, 0.f};
        a1[e] = cvt4(t1);
        f32x4 t2;                              // A2[row=col][k=kb+i] = W2[e][kb+i][col]
        #pragma unroll
        for (int i = 0; i < 4; ++i) t2[i] = W2[e * 256 + (kb + i) * 16 + col];
        a2[e] = cvt4(t2);
        f32x4 t3;                              // A3[row=col][k=kb+i] = W3[e][kb+i]
        #pragma unroll
        for (int i = 0; i < 4; ++i) t3[i] = W3[e * 16 + kb + i];
        a3[e] = cvt4(t3);
        #pragma unroll
        for (int r = 0; r < 4; ++r) c2[e][r] = b2[e * 16 + kb + r];
    }
    const float b3g = (g < 3) ? b3[g] : 0.f;
    const f32x4 cz = {0.f, 0.f, 0.f, 0.f};

    const int xoff = (wv * 64 + col) * 8;          // + tile*128 imm
    const int ooff = (wv * 192 + col * 3 + g) * 4; // + tile*192 imm (g<3 only)
    const bool gz = (g == 0);

    const int nblk = n >> 8;                       // 256 points per block-iter
    for (int cb = blockIdx.x; cb < nblk; cb += gridDim.x) {
        const char* xb = (const char*)x + (size_t)cb * 2048;
        char*       ob = (char*)out + (size_t)cb * 3072;

        #pragma unroll
        for (int half = 0; half < 2; ++half) {
            const float2 xv0 = *reinterpret_cast<const float2*>(xb + xoff + (2 * half + 0) * 128);
            const float2 xv1 = *reinterpret_cast<const float2*>(xb + xoff + (2 * half + 1) * 128);
            f32x4 xs0 = {0.f, 0.f, 0.f, 0.f}, xs1 = {0.f, 0.f, 0.f, 0.f};
            if (gz) {
                xs0[0] = xv0.x; xs0[1] = xv0.y; xs0[2] = 1.0f;   // 1.0 -> b1 K-slot
                xs1[0] = xv1.x; xs1[1] = xv1.y; xs1[2] = 1.0f;
            }
            const s16x4 bx0 = cvt4(xs0), bx1 = cvt4(xs1);

            float y0 = b3g, y1 = b3g;
            #pragma unroll
            for (int e = 0; e < 3; ++e) {
                f32x4 h0 = MFMA16(a1[e], bx0, cz);
                f32x4 h1 = MFMA16(a1[e], bx1, cz);
                f32x4 r0, r1;
                #pragma unroll
                for (int r = 0; r < 4; ++r) { r0[r] = fmaxf(h0[r], 0.f); r1[r] = fmaxf(h1[r], 0.f); }
                s16x4 p0 = cvt4(r0), p1 = cvt4(r1);
                h0 = MFMA16(a2[e], p0, c2[e]);
                h1 = MFMA16(a2[e], p1, c2[e]);
                #pragma unroll
                for (int r = 0; r < 4; ++r) { r0[r] = fmaxf(h0[r], 0.f); r1[r] = fmaxf(h1[r], 0.f); }
                p0 = cvt4(r0); p1 = cvt4(r1);
                h0 = MFMA16(a3[e], p0, cz);
                h1 = MFMA16(a3[e], p1, cz);
                y0 = (g == e) ? y0 + h0[0] : y0;   // masks hoisted by compiler
                y1 = (g == e) ? y1 + h1[0] : y1;
            }

            if (g < 3) {
                *reinterpret_cast<float*>(ob + ooff + (2 * half + 0) * 192) = y0;
                *reinterpret_cast<float*>(ob + ooff + (2 * half + 1) * 192) = y1;
            }
        }
    }
}

extern "C" void kernel_launch(void* const* d_in, const int* in_sizes, int n_in,
                              void* d_out, int out_size, void* d_ws, size_t ws_size,
                              hipStream_t stream) {
    const float* x  = (const float*)d_in[0];
    const float* W1 = (const float*)d_in[1];
    const float* b1 = (const float*)d_in[2];
    const float* W2 = (const float*)d_in[3];
    const float* b2 = (const float*)d_in[4];
    const float* W3 = (const float*)d_in[5];
    const float* b3 = (const float*)d_in[6];
    float* out = (float*)d_out;
    (void)d_ws; (void)ws_size; (void)n_in; (void)out_size;

    const int n = in_sizes[0] / 2;   // 4194304 points (16384 * 256)
    const int block = 256;
    const int grid = 2048;           // 8 blocks/CU; 8 chunk-iterations each

    mlp3_mfma<<<grid, block, 0, stream>>>(x, W1, b1, W2, b2, W3, b3, out, n);
}

// Round 6
// 58.265 us; speedup vs baseline: 2.0273x; 1.0261x over previous
//
#include <hip/hip_runtime.h>
#include <hip/hip_bf16.h>

typedef __attribute__((ext_vector_type(4))) float f32x4;
typedef __attribute__((ext_vector_type(4))) short s16x4;
typedef __attribute__((ext_vector_type(4))) __bf16 bf16x4;

// f32x4 -> 4 bf16 (RNE), compiler-lowered.
static __device__ __forceinline__ s16x4 cvt4(f32x4 v) {
    return __builtin_bit_cast(s16x4, __builtin_convertvector(v, bf16x4));
}

#define MFMA16(A, B, C) __builtin_amdgcn_mfma_f32_16x16x16bf16_1k((A), (B), (C), 0, 0, 0)

// All transposed, col = point. D-layout == B-layout identity chains the MFMAs.
//   MFMA1: D1[k][p] = W1^T x^T (+ b1 via K-slot 2; x K-slot 2 = 1.0), C = 0.
//          No x masking: A1 k>=4 slots are 0.0, so 0*anything = 0.
//   MFMA2: D2[j][p] = W2^T relu(D1) + b2 (C = b2)
//   MFMA3 x3, chained C, row-selective A3: A3_e[row][k] = (row==e) ? w3_e[k] : 0.
//          y quad = MFMA(a3[2], t2, MFMA(a3[1], t1, MFMA(a3[0], t0, c30)));
//          c30 rows 0..2 = b3. Final: g==0 lanes hold (y0,y1,y2) in regs 0..2.
__global__ __launch_bounds__(256, 8) void mlp3_mfma(
    const float* __restrict__ x,
    const float* __restrict__ W1, const float* __restrict__ b1,
    const float* __restrict__ W2, const float* __restrict__ b2,
    const float* __restrict__ W3, const float* __restrict__ b3,
    float* __restrict__ out, int n)
{
    const int tid  = (int)threadIdx.x;
    const int lane = tid & 63;
    const int col  = lane & 15;   // matrix column = point; row index for A frags
    const int g    = lane >> 4;   // k-slice group
    const int kb   = g << 2;
    const int wv   = tid >> 6;

    // ---- weight fragments (loaded once, resident) ----
    s16x4 a1[3], a2[3], a3[3];
    f32x4 c2[3];
    #pragma unroll
    for (int e = 0; e < 3; ++e) {
        float w1a = 0.f, w1b = 0.f, w1c = 0.f;
        if (g == 0) {                       // A1 row=col(hid), k: 0=W1[0], 1=W1[1], 2=b1
            w1a = W1[e * 32 + col];
            w1b = W1[e * 32 + 16 + col];
            w1c = b1[e * 16 + col];
        }
        f32x4 t1 = {w1a, w1b, w1c, 0.f};
        a1[e] = cvt4(t1);
        f32x4 t2;                            // A2[row=col][k=kb+i] = W2[e][kb+i][col]
        #pragma unroll
        for (int i = 0; i < 4; ++i) t2[i] = W2[e * 256 + (kb + i) * 16 + col];
        a2[e] = cvt4(t2);
        f32x4 t3 = {0.f, 0.f, 0.f, 0.f};     // A3_e row-selective: only row(=col)==e
        if (col == e) {
            #pragma unroll
            for (int i = 0; i < 4; ++i) t3[i] = W3[e * 16 + kb + i];
        }
        a3[e] = cvt4(t3);
        #pragma unroll
        for (int r = 0; r < 4; ++r) c2[e][r] = b2[e * 16 + kb + r];
    }
    // C3 seed: rows 0..2 (g==0, regs 0..2) get b3; all else 0.
    f32x4 c30 = {0.f, 0.f, 0.f, 0.f};
    if (g == 0) { c30[0] = b3[0]; c30[1] = b3[1]; c30[2] = b3[2]; }
    const f32x4 cz = {0.f, 0.f, 0.f, 0.f};

    const int xoff = (wv * 64 + col) * 8;    // bytes; + tile*128 imm
    const int ooff = wv * 768 + col * 12;    // bytes; + tile*192 imm (g==0 only)
    const bool gz = (g == 0);

    const int nblk = n >> 8;                 // 256 points per block-iter
    for (int cb = blockIdx.x; cb < nblk; cb += gridDim.x) {
        const char* xb = (const char*)x + (size_t)cb * 2048;
        char*       ob = (char*)out + (size_t)cb * 3072;

        #pragma unroll
        for (int half = 0; half < 2; ++half) {
            const float2 xv0 = *reinterpret_cast<const float2*>(xb + xoff + (2 * half + 0) * 128);
            const float2 xv1 = *reinterpret_cast<const float2*>(xb + xoff + (2 * half + 1) * 128);
            f32x4 xs0 = {xv0.x, xv0.y, 1.0f, 0.f};   // K-slot 2 = 1.0 -> b1
            f32x4 xs1 = {xv1.x, xv1.y, 1.0f, 0.f};
            const s16x4 bx0 = cvt4(xs0), bx1 = cvt4(xs1);

            f32x4 y0 = c30, y1 = c30;
            #pragma unroll
            for (int e = 0; e < 3; ++e) {
                f32x4 h0 = MFMA16(a1[e], bx0, cz);
                f32x4 h1 = MFMA16(a1[e], bx1, cz);
                f32x4 r0, r1;
                #pragma unroll
                for (int r = 0; r < 4; ++r) { r0[r] = fmaxf(h0[r], 0.f); r1[r] = fmaxf(h1[r], 0.f); }
                s16x4 p0 = cvt4(r0), p1 = cvt4(r1);
                h0 = MFMA16(a2[e], p0, c2[e]);
                h1 = MFMA16(a2[e], p1, c2[e]);
                #pragma unroll
                for (int r = 0; r < 4; ++r) { r0[r] = fmaxf(h0[r], 0.f); r1[r] = fmaxf(h1[r], 0.f); }
                p0 = cvt4(r0); p1 = cvt4(r1);
                y0 = MFMA16(a3[e], p0, y0);   // chained C; adds into row e only
                y1 = MFMA16(a3[e], p1, y1);
            }

            if (gz) {
                float* o0 = reinterpret_cast<float*>(ob + ooff + (2 * half + 0) * 192);
                float* o1 = reinterpret_cast<float*>(ob + ooff + (2 * half + 1) * 192);
                o0[0] = y0[0]; o0[1] = y0[1]; o0[2] = y0[2];
                o1[0] = y1[0]; o1[1] = y1[1]; o1[2] = y1[2];
            }
        }
    }
}

extern "C" void kernel_launch(void* const* d_in, const int* in_sizes, int n_in,
                              void* d_out, int out_size, void* d_ws, size_t ws_size,
                              hipStream_t stream) {
    const float* x  = (const float*)d_in[0];
    const float* W1 = (const float*)d_in[1];
    const float* b1 = (const float*)d_in[2];
    const float* W2 = (const float*)d_in[3];
    const float* b2 = (const float*)d_in[4];
    const float* W3 = (const float*)d_in[5];
    const float* b3 = (const float*)d_in[6];
    float* out = (float*)d_out;
    (void)d_ws; (void)ws_size; (void)n_in; (void)out_size;

    const int n = in_sizes[0] / 2;   // 4194304 points (16384 * 256)
    const int block = 256;
    const int grid = 2048;           // 8 blocks/CU; 8 chunk-iterations each

    mlp3_mfma<<<grid, block, 0, stream>>>(x, W1, b1, W2, b2, W3, b3, out, n);
}

// Round 7
// 57.682 us; speedup vs baseline: 2.0477x; 1.0101x over previous
//
#include <hip/hip_runtime.h>
#include <hip/hip_bf16.h>

typedef __attribute__((ext_vector_type(4))) float f32x4;
typedef __attribute__((ext_vector_type(4))) short s16x4;
typedef __attribute__((ext_vector_type(4))) __bf16 bf16x4;

// f32x4 -> 4 bf16 (RNE), compiler-lowered.
static __device__ __forceinline__ s16x4 cvt4(f32x4 v) {
    return __builtin_bit_cast(s16x4, __builtin_convertvector(v, bf16x4));
}

#define MFMA16(A, B, C) __builtin_amdgcn_mfma_f32_16x16x16bf16_1k((A), (B), (C), 0, 0, 0)

// All transposed, col = point. 16x16 D-layout == B-layout identity chains MFMAs.
//   MFMA1: D1[k][p] = W1^T x^T (+ b1 via K-slot 2; x K-slot 2 = 1.0), C = 0
//   MFMA2: D2[j][p] = W2^T relu(D1) + b2
//   MFMA3: chained C, row-selective A3 (row e = w3_e) -> g==0 lanes end with
//          (y0,y1,y2) in regs 0..2.  ILP=4 tiles per wave, stage-interleaved;
//   next-iteration x prefetched into registers (issue-early).
__global__ __launch_bounds__(256, 4) void mlp3_mfma(
    const float* __restrict__ x,
    const float* __restrict__ W1, const float* __restrict__ b1,
    const float* __restrict__ W2, const float* __restrict__ b2,
    const float* __restrict__ W3, const float* __restrict__ b3,
    float* __restrict__ out, int n)
{
    const int tid  = (int)threadIdx.x;
    const int lane = tid & 63;
    const int col  = lane & 15;   // matrix column = point; row index for A frags
    const int g    = lane >> 4;   // k-slice group
    const int kb   = g << 2;
    const int wv   = tid >> 6;

    // ---- weight fragments (loaded once, resident) ----
    s16x4 a1[3], a2[3], a3[3];
    f32x4 c2[3];
    #pragma unroll
    for (int e = 0; e < 3; ++e) {
        float w1a = 0.f, w1b = 0.f, w1c = 0.f;
        if (g == 0) {                       // A1 row=col(hid), k: 0=W1[0], 1=W1[1], 2=b1
            w1a = W1[e * 32 + col];
            w1b = W1[e * 32 + 16 + col];
            w1c = b1[e * 16 + col];
        }
        f32x4 t1 = {w1a, w1b, w1c, 0.f};
        a1[e] = cvt4(t1);
        f32x4 t2;                            // A2[row=col][k=kb+i] = W2[e][kb+i][col]
        #pragma unroll
        for (int i = 0; i < 4; ++i) t2[i] = W2[e * 256 + (kb + i) * 16 + col];
        a2[e] = cvt4(t2);
        f32x4 t3 = {0.f, 0.f, 0.f, 0.f};     // A3_e row-selective: only row(=col)==e
        if (col == e) {
            #pragma unroll
            for (int i = 0; i < 4; ++i) t3[i] = W3[e * 16 + kb + i];
        }
        a3[e] = cvt4(t3);
        #pragma unroll
        for (int r = 0; r < 4; ++r) c2[e][r] = b2[e * 16 + kb + r];
    }
    f32x4 c30 = {0.f, 0.f, 0.f, 0.f};        // C3 seed: g==0 regs 0..2 = b3
    if (g == 0) { c30[0] = b3[0]; c30[1] = b3[1]; c30[2] = b3[2]; }
    const f32x4 cz = {0.f, 0.f, 0.f, 0.f};

    const int xoff = (wv * 64 + col) * 8;    // bytes; + tile*128 imm
    const int ooff = wv * 768 + col * 12;    // bytes; + tile*192 imm (g==0 only)
    const bool gz = (g == 0);

    const int nblk   = n >> 8;               // 16384 chunk-iters of 256 points
    const int stride = (int)gridDim.x;

    int cb = (int)blockIdx.x;
    const char* xb = (const char*)x + (size_t)cb * 2048;
    float2 xv[4];
    #pragma unroll
    for (int t = 0; t < 4; ++t)
        xv[t] = *reinterpret_cast<const float2*>(xb + xoff + t * 128);

    while (true) {
        const int nb = cb + stride;
        const bool more = nb < nblk;
        float2 xn[4];
        if (more) {                           // prefetch next chunk's x (issue-early)
            const char* xb2 = (const char*)x + (size_t)nb * 2048;
            #pragma unroll
            for (int t = 0; t < 4; ++t)
                xn[t] = *reinterpret_cast<const float2*>(xb2 + xoff + t * 128);
        }

        // ---- compute current chunk: 4 independent tile chains, stage-interleaved ----
        s16x4 bx[4], p[4];
        f32x4 h[4], y[4];
        #pragma unroll
        for (int t = 0; t < 4; ++t) {
            f32x4 xs = {xv[t].x, xv[t].y, 1.0f, 0.f};   // K-slot 2 = 1.0 -> b1
            bx[t] = cvt4(xs);
            y[t] = c30;
        }
        #pragma unroll
        for (int e = 0; e < 3; ++e) {
            #pragma unroll
            for (int t = 0; t < 4; ++t) h[t] = MFMA16(a1[e], bx[t], cz);
            #pragma unroll
            for (int t = 0; t < 4; ++t) {
                f32x4 r;
                #pragma unroll
                for (int r4 = 0; r4 < 4; ++r4) r[r4] = fmaxf(h[t][r4], 0.f);
                p[t] = cvt4(r);
            }
            #pragma unroll
            for (int t = 0; t < 4; ++t) h[t] = MFMA16(a2[e], p[t], c2[e]);
            #pragma unroll
            for (int t = 0; t < 4; ++t) {
                f32x4 r;
                #pragma unroll
                for (int r4 = 0; r4 < 4; ++r4) r[r4] = fmaxf(h[t][r4], 0.f);
                p[t] = cvt4(r);
            }
            #pragma unroll
            for (int t = 0; t < 4; ++t) y[t] = MFMA16(a3[e], p[t], y[t]);
        }

        if (gz) {
            char* ob = (char*)out + (size_t)cb * 3072;
            #pragma unroll
            for (int t = 0; t < 4; ++t) {
                float* o = reinterpret_cast<float*>(ob + ooff + t * 192);
                o[0] = y[t][0]; o[1] = y[t][1]; o[2] = y[t][2];
            }
        }

        if (!more) break;
        cb = nb;
        #pragma unroll
        for (int t = 0; t < 4; ++t) xv[t] = xn[t];
    }
}

extern "C" void kernel_launch(void* const* d_in, const int* in_sizes, int n_in,
                              void* d_out, int out_size, void* d_ws, size_t ws_size,
                              hipStream_t stream) {
    const float* x  = (const float*)d_in[0];
    const float* W1 = (const float*)d_in[1];
    const float* b1 = (const float*)d_in[2];
    const float* W2 = (const float*)d_in[3];
    const float* b2 = (const float*)d_in[4];
    const float* W3 = (const float*)d_in[5];
    const float* b3 = (const float*)d_in[6];
    float* out = (float*)d_out;
    (void)d_ws; (void)ws_size; (void)n_in; (void)out_size;

    const int n = in_sizes[0] / 2;   // 4194304 points (16384 * 256)
    const int block = 256;
    const int grid = 2048;           // 8 chunk-iterations per block

    mlp3_mfma<<<grid, block, 0, stream>>>(x, W1, b1, W2, b2, W3, b3, out, n);
}

// Round 10
// 55.754 us; speedup vs baseline: 2.1185x; 1.0346x over previous
//
#include <hip/hip_runtime.h>
#include <hip/hip_bf16.h>

typedef __attribute__((ext_vector_type(2)))  float f32x2;
typedef __attribute__((ext_vector_type(4)))  float f32x4;
typedef __attribute__((ext_vector_type(8)))  float f32x8;
typedef __attribute__((ext_vector_type(16))) float f32x16;
typedef __attribute__((ext_vector_type(2)))  __bf16 bf16x2;
typedef __attribute__((ext_vector_type(8)))  __bf16 bf16x8;
typedef __attribute__((ext_vector_type(4)))  unsigned int u32x4;
typedef __attribute__((ext_vector_type(2)))  int i32x2;

// Cold path: f32x8 -> bf16x8, compiler-lowered (validated R4-R7 path).
static __device__ __forceinline__ bf16x8 cvt8(f32x8 v) {
    return __builtin_convertvector(v, bf16x8);
}
// Pair-pack f32,f32 -> one u32 of 2 bf16 (RNE), compiler-lowered, bit_cast-safe.
static __device__ __forceinline__ unsigned int pk2(float a, float b) {
    f32x2 v = {a, b};
    return __builtin_bit_cast(unsigned int, __builtin_convertvector(v, bf16x2));
}

#define MFMA32(A, B, C) __builtin_amdgcn_mfma_f32_32x32x16_bf16((A), (B), (C), 0, 0, 0)

// D(32x32) -> next B(K=16) redistribution:
//   D regs r<8 hold rows {0..3,8..11}+4h (h = lane>>5), col = lane&31.
//   B frag needs elem e = matrix[k=8h+e][col].
//   q0=pk(d0,d1) q1=pk(d2,d3) (rows 0..3+4h), q2=pk(d4,d5) q3=pk(d6,d7) (rows 8..11+4h).
//   permlane32_swap(q0,q2) = {B01, B45}; swap(q1,q3) = {B23, B67}.
static __device__ __forceinline__ bf16x8 pack_frag(
    float d0, float d1, float d2, float d3,
    float d4, float d5, float d6, float d7) {
    unsigned int q0 = pk2(d0, d1), q1 = pk2(d2, d3);
    unsigned int q2 = pk2(d4, d5), q3 = pk2(d6, d7);
    i32x2 s02 = __builtin_amdgcn_permlane32_swap((int)q0, (int)q2, false, false);
    i32x2 s13 = __builtin_amdgcn_permlane32_swap((int)q1, (int)q3, false, false);
    u32x4 u = { (unsigned)s02[0], (unsigned)s13[0], (unsigned)s02[1], (unsigned)s13[1] };
    return __builtin_bit_cast(bf16x8, u);
}

// Native 32x32x16 bf16 chain, 32 points per wave-tile, transposed (col = point):
//   L1: D1[hid][p] = W1^T x^T (b1 via K-slot 2; x K-slot 2 = 1.0), C = 0
//   L2: D2[j][p]   = W2^T relu(D1); b2 + relu in VALU (regs 0..7 only)
//   L3: chained C, row-selective A3 (row e = w3_e) -> lanes<32 end with
//       (y0,y1,y2) in regs 0..2; b3 added at store.
__global__ __launch_bounds__(256, 3) void mlp3_mfma32(
    const float* __restrict__ x,
    const float* __restrict__ W1, const float* __restrict__ b1,
    const float* __restrict__ W2, const float* __restrict__ b2,
    const float* __restrict__ W3, const float* __restrict__ b3,
    float* __restrict__ out, int n)
{
    const int tid  = (int)threadIdx.x;
    const int lane = tid & 63;
    const int row  = lane & 31;   // A-frag row / B col (point)
    const int h    = lane >> 5;   // K-half: k = 8h + elem
    const int wv   = tid >> 6;

    // ---- weight fragments (cold init, resident) ----
    bf16x8 a1[3], a2[3], a3[3];
    f32x4 b2lo[3], b2hi[3];
    #pragma unroll
    for (int e = 0; e < 3; ++e) {
        f32x8 t = {0.f,0.f,0.f,0.f,0.f,0.f,0.f,0.f};
        if (h == 0 && row < 16) {
            t[0] = W1[e * 32 + row];        // k=0: W1[e][0][row]
            t[1] = W1[e * 32 + 16 + row];   // k=1: W1[e][1][row]
            t[2] = b1[e * 16 + row];        // k=2: b1 (x K-slot 2 = 1.0)
        }
        a1[e] = cvt8(t);
        f32x8 t2 = {0.f,0.f,0.f,0.f,0.f,0.f,0.f,0.f};
        if (row < 16) {
            #pragma unroll
            for (int i = 0; i < 8; ++i)
                t2[i] = W2[e * 256 + (8 * h + i) * 16 + row];  // A2[j=row][k=8h+i]
        }
        a2[e] = cvt8(t2);
        f32x8 t3 = {0.f,0.f,0.f,0.f,0.f,0.f,0.f,0.f};
        if (row == e) {
            #pragma unroll
            for (int i = 0; i < 8; ++i)
                t3[i] = W3[e * 16 + 8 * h + i];                // A3_e[row=e][k]
        }
        a3[e] = cvt8(t3);
        #pragma unroll
        for (int r = 0; r < 4; ++r) {
            b2lo[e][r] = b2[e * 16 + (r & 3) + 4 * h];          // rows (r&3)+4h
            b2hi[e][r] = b2[e * 16 + (r & 3) + 8 + 4 * h];      // rows (r&3)+8+4h
        }
    }
    const float b30 = b3[0], b31 = b3[1], b32 = b3[2];
    f32x16 zz;
    #pragma unroll
    for (int r = 0; r < 16; ++r) zz[r] = 0.f;

    const int xoff = (wv * 32 + row) * 8;    // bytes into 1024B x-chunk
    const int ooff = (wv * 32 + row) * 12;   // bytes into 1536B out-chunk (lane<32)

    const int nblk   = n >> 7;               // 128 points per block-iter
    const int stride = (int)gridDim.x;

    int cb = (int)blockIdx.x;
    float2 xv = *reinterpret_cast<const float2*>(
        (const char*)x + (size_t)cb * 1024 + xoff);

    while (true) {
        const int nb = cb + stride;
        const bool more = nb < nblk;
        float2 xn;
        if (more)                             // prefetch next iter's x
            xn = *reinterpret_cast<const float2*>(
                (const char*)x + (size_t)nb * 1024 + xoff);

        // B1: k-slots {x0, x1, 1.0, 0...}; h=1 half garbage-safe (A1 zero there)
        u32x4 bxu = { pk2(xv.x, xv.y), 0x3F80u, 0u, 0u };
        const bf16x8 bx = __builtin_bit_cast(bf16x8, bxu);

        f32x16 y = zz;
        #pragma unroll
        for (int e = 0; e < 3; ++e) {
            f32x16 t1 = MFMA32(a1[e], bx, zz);
            bf16x8 bh = pack_frag(
                fmaxf(t1[0], 0.f), fmaxf(t1[1], 0.f), fmaxf(t1[2], 0.f), fmaxf(t1[3], 0.f),
                fmaxf(t1[4], 0.f), fmaxf(t1[5], 0.f), fmaxf(t1[6], 0.f), fmaxf(t1[7], 0.f));
            f32x16 t2 = MFMA32(a2[e], bh, zz);
            bf16x8 bt = pack_frag(
                fmaxf(t2[0] + b2lo[e][0], 0.f), fmaxf(t2[1] + b2lo[e][1], 0.f),
                fmaxf(t2[2] + b2lo[e][2], 0.f), fmaxf(t2[3] + b2lo[e][3], 0.f),
                fmaxf(t2[4] + b2hi[e][0], 0.f), fmaxf(t2[5] + b2hi[e][1], 0.f),
                fmaxf(t2[6] + b2hi[e][2], 0.f), fmaxf(t2[7] + b2hi[e][3], 0.f));
            y = MFMA32(a3[e], bt, y);         // adds into row e only (chained C)
        }

        if (lane < 32) {                      // h=0: regs 0..2 = rows 0..2 = heads
            float3 o = make_float3(y[0] + b30, y[1] + b31, y[2] + b32);
            *reinterpret_cast<float3*>(
                (char*)out + (size_t)cb * 1536 + ooff) = o;
        }

        if (!more) break;
        cb = nb;
        xv = xn;
    }
}

extern "C" void kernel_launch(void* const* d_in, const int* in_sizes, int n_in,
                              void* d_out, int out_size, void* d_ws, size_t ws_size,
                              hipStream_t stream) {
    const float* x  = (const float*)d_in[0];
    const float* W1 = (const float*)d_in[1];
    const float* b1 = (const float*)d_in[2];
    const float* W2 = (const float*)d_in[3];
    const float* b2 = (const float*)d_in[4];
    const float* W3 = (const float*)d_in[5];
    const float* b3 = (const float*)d_in[6];
    float* out = (float*)d_out;
    (void)d_ws; (void)ws_size; (void)n_in; (void)out_size;

    const int n = in_sizes[0] / 2;   // 4194304 points (32768 * 128)
    const int block = 256;
    const int grid = 2048;           // 16 chunk-iterations per block

    mlp3_mfma32<<<grid, block, 0, stream>>>(x, W1, b1, W2, b2, W3, b3, out, n);
}

// Round 11
// 49.830 us; speedup vs baseline: 2.3704x; 1.1189x over previous
//
#include <hip/hip_runtime.h>
#include <hip/hip_bf16.h>

typedef __attribute__((ext_vector_type(2)))  float f32x2;
typedef __attribute__((ext_vector_type(4)))  float f32x4;
typedef __attribute__((ext_vector_type(8)))  float f32x8;
typedef __attribute__((ext_vector_type(16))) float f32x16;
typedef __attribute__((ext_vector_type(2)))  __bf16 bf16x2;
typedef __attribute__((ext_vector_type(8)))  __bf16 bf16x8;
typedef __attribute__((ext_vector_type(4)))  unsigned int u32x4;

// f32x8 -> bf16x8, compiler-lowered (cold path).
static __device__ __forceinline__ bf16x8 cvt8(f32x8 v) {
    return __builtin_convertvector(v, bf16x8);
}
// Pair-pack f32,f32 -> u32 of 2 bf16 (RNE), compiler-lowered.
static __device__ __forceinline__ unsigned int pk2(float a, float b) {
    f32x2 v = {a, b};
    return __builtin_bit_cast(unsigned int, __builtin_convertvector(v, bf16x2));
}

#define MFMA32(A, B, C) __builtin_amdgcn_mfma_f32_32x32x16_bf16((A), (B), (C), 0, 0, 0)

// D(32x32) regs 0..7 of lane-group h hold rows kperm(h,r) = (r&3)+8*(r>>2)+4h —
// a bijection on k in [0,16). We pack D regs 0..7 pairwise as the next B-frag
// (same lane, same reg order) and absorb the permutation into A2/A3's K-order
// at init. NO cross-lane ops in the hot loop.
static __device__ __forceinline__ bf16x8 relu_pack(const f32x16& t) {
    u32x4 u = { pk2(fmaxf(t[0], 0.f), fmaxf(t[1], 0.f)),
                pk2(fmaxf(t[2], 0.f), fmaxf(t[3], 0.f)),
                pk2(fmaxf(t[4], 0.f), fmaxf(t[5], 0.f)),
                pk2(fmaxf(t[6], 0.f), fmaxf(t[7], 0.f)) };
    return __builtin_bit_cast(bf16x8, u);
}
static __device__ __forceinline__ bf16x8 relu_pack_b2(const f32x16& t,
                                                      const f32x4& lo, const f32x4& hi) {
    u32x4 u = { pk2(fmaxf(t[0] + lo[0], 0.f), fmaxf(t[1] + lo[1], 0.f)),
                pk2(fmaxf(t[2] + lo[2], 0.f), fmaxf(t[3] + lo[3], 0.f)),
                pk2(fmaxf(t[4] + hi[0], 0.f), fmaxf(t[5] + hi[1], 0.f)),
                pk2(fmaxf(t[6] + hi[2], 0.f), fmaxf(t[7] + hi[3], 0.f)) };
    return __builtin_bit_cast(bf16x8, u);
}

// Native 32x32x16 bf16 chain, 2 tiles (64 pts) per wave-iter, transposed:
//   L1: D1[hid][p] = W1^T x^T (b1 via K-slot 2; x K-slot 2 = 1.0), C = zz
//   L2: D2[j][p]   = W2'^T relu(D1) (A2 k-permuted), b2+relu in VALU
//   L3: chained C, row-selective k-permuted A3 -> lanes<32 end with
//       (y0,y1,y2) in regs 0..2; b3 added at store.
__global__ __launch_bounds__(256, 3) void mlp3_mfma32(
    const float* __restrict__ x,
    const float* __restrict__ W1, const float* __restrict__ b1,
    const float* __restrict__ W2, const float* __restrict__ b2,
    const float* __restrict__ W3, const float* __restrict__ b3,
    float* __restrict__ out, int n)
{
    const int tid  = (int)threadIdx.x;
    const int lane = tid & 63;
    const int row  = lane & 31;   // A-frag row / B col (point)
    const int h    = lane >> 5;   // K-half selector in frag layouts
    const int wv   = tid >> 6;

    // ---- weight fragments (cold init, resident) ----
    bf16x8 a1[3], a2[3], a3[3];
    f32x4 b2lo[3], b2hi[3];
    #pragma unroll
    for (int e = 0; e < 3; ++e) {
        f32x8 t = {0.f,0.f,0.f,0.f,0.f,0.f,0.f,0.f};
        if (h == 0 && row < 16) {
            t[0] = W1[e * 32 + row];        // k=0: W1[e][0][row]
            t[1] = W1[e * 32 + 16 + row];   // k=1: W1[e][1][row]
            t[2] = b1[e * 16 + row];        // k=2: b1 (x K-slot 2 = 1.0)
        }
        a1[e] = cvt8(t);
        f32x8 t2 = {0.f,0.f,0.f,0.f,0.f,0.f,0.f,0.f};
        if (row < 16) {
            #pragma unroll
            for (int i = 0; i < 8; ++i) {
                const int k = (i & 3) + 8 * (i >> 2) + 4 * h;   // kperm(h,i)
                t2[i] = W2[e * 256 + k * 16 + row];
            }
        }
        a2[e] = cvt8(t2);
        f32x8 t3 = {0.f,0.f,0.f,0.f,0.f,0.f,0.f,0.f};
        if (row == e) {
            #pragma unroll
            for (int i = 0; i < 8; ++i) {
                const int k = (i & 3) + 8 * (i >> 2) + 4 * h;   // kperm(h,i)
                t3[i] = W3[e * 16 + k];
            }
        }
        a3[e] = cvt8(t3);
        #pragma unroll
        for (int r = 0; r < 4; ++r) {
            b2lo[e][r] = b2[e * 16 + r + 4 * h];        // rows r+4h      (regs 0..3)
            b2hi[e][r] = b2[e * 16 + r + 8 + 4 * h];    // rows r+8+4h    (regs 4..7)
        }
    }
    const float b30 = b3[0], b31 = b3[1], b32 = b3[2];
    f32x16 zz;
    #pragma unroll
    for (int r = 0; r < 16; ++r) zz[r] = 0.f;

    const int xoff = (wv * 64 + row) * 8;    // bytes into 2048B x-chunk; tile1 = +256
    const int ooff = (wv * 64 + row) * 12;   // bytes into 3072B out-chunk; tile1 = +384

    const int nblk   = n >> 8;               // 256 points per block-iter
    const int stride = (int)gridDim.x;

    int cb = (int)blockIdx.x;
    float2 xv0 = *reinterpret_cast<const float2*>((const char*)x + (size_t)cb * 2048 + xoff);
    float2 xv1 = *reinterpret_cast<const float2*>((const char*)x + (size_t)cb * 2048 + xoff + 256);

    while (true) {
        const int nb = cb + stride;
        const bool more = nb < nblk;
        float2 xn0, xn1;
        if (more) {                           // prefetch next iter's x
            xn0 = *reinterpret_cast<const float2*>((const char*)x + (size_t)nb * 2048 + xoff);
            xn1 = *reinterpret_cast<const float2*>((const char*)x + (size_t)nb * 2048 + xoff + 256);
        }

        // B1: k-slots {x0, x1, 1.0, 0...}; h=1 half garbage-safe (A1 zero there)
        u32x4 bu0 = { pk2(xv0.x, xv0.y), 0x3F80u, 0u, 0u };
        u32x4 bu1 = { pk2(xv1.x, xv1.y), 0x3F80u, 0u, 0u };
        const bf16x8 bx0 = __builtin_bit_cast(bf16x8, bu0);
        const bf16x8 bx1 = __builtin_bit_cast(bf16x8, bu1);

        f32x16 y0, y1;
        #pragma unroll
        for (int e = 0; e < 3; ++e) {
            f32x16 t10 = MFMA32(a1[e], bx0, zz);
            f32x16 t11 = MFMA32(a1[e], bx1, zz);
            bf16x8 bh0 = relu_pack(t10);
            bf16x8 bh1 = relu_pack(t11);
            f32x16 t20 = MFMA32(a2[e], bh0, zz);
            f32x16 t21 = MFMA32(a2[e], bh1, zz);
            bf16x8 bt0 = relu_pack_b2(t20, b2lo[e], b2hi[e]);
            bf16x8 bt1 = relu_pack_b2(t21, b2lo[e], b2hi[e]);
            if (e == 0) {                     // fresh D: no y init movs
                y0 = MFMA32(a3[0], bt0, zz);
                y1 = MFMA32(a3[0], bt1, zz);
            } else {                          // in-place chained C
                y0 = MFMA32(a3[e], bt0, y0);
                y1 = MFMA32(a3[e], bt1, y1);
            }
        }

        if (lane < 32) {                      // h=0: regs 0..2 = rows 0..2 = heads
            char* ob = (char*)out + (size_t)cb * 3072 + ooff;
            *reinterpret_cast<float3*>(ob) =
                make_float3(y0[0] + b30, y0[1] + b31, y0[2] + b32);
            *reinterpret_cast<float3*>(ob + 384) =
                make_float3(y1[0] + b30, y1[1] + b31, y1[2] + b32);
        }

        if (!more) break;
        cb = nb;
        xv0 = xn0; xv1 = xn1;
    }
}

extern "C" void kernel_launch(void* const* d_in, const int* in_sizes, int n_in,
                              void* d_out, int out_size, void* d_ws, size_t ws_size,
                              hipStream_t stream) {
    const float* x  = (const float*)d_in[0];
    const float* W1 = (const float*)d_in[1];
    const float* b1 = (const float*)d_in[2];
    const float* W2 = (const float*)d_in[3];
    const float* b2 = (const float*)d_in[4];
    const float* W3 = (const float*)d_in[5];
    const float* b3 = (const float*)d_in[6];
    float* out = (float*)d_out;
    (void)d_ws; (void)ws_size; (void)n_in; (void)out_size;

    const int n = in_sizes[0] / 2;   // 4194304 points (16384 * 256)
    const int block = 256;
    const int grid = 2048;           // 8 chunk-iterations per block

    mlp3_mfma32<<<grid, block, 0, stream>>>(x, W1, b1, W2, b2, W3, b3, out, n);
}